// Round 2
// baseline (592.242 us; speedup 1.0000x reference)
//
#include <hip/hip_runtime.h>
#include <hip/hip_bf16.h>
#include <math.h>

typedef __bf16 bf16x8 __attribute__((ext_vector_type(8)));
typedef __bf16 bf16x4 __attribute__((ext_vector_type(4)));
typedef float floatx4 __attribute__((ext_vector_type(4)));

#define NQS   2048
#define NKVS  2048
#define NKV1  2049
#define DM    1024
#define NH    16
#define DHD   64
#define BATCH 2

// ---------------------------------------------------------------------------
// LayerNorm (f32 in) -> bf16 out.  One block per row of 1024.
// ---------------------------------------------------------------------------
__global__ __launch_bounds__(256) void ln_to_bf16(
    const float* __restrict__ X, const float* __restrict__ gamma,
    const float* __restrict__ beta, __bf16* __restrict__ out)
{
    const int row = blockIdx.x;
    const int tid = threadIdx.x;
    const float4 v = ((const float4*)(X + (size_t)row * DM))[tid];
    float s  = v.x + v.y + v.z + v.w;
    float sq = v.x * v.x + v.y * v.y + v.z * v.z + v.w * v.w;
    for (int off = 1; off < 64; off <<= 1) {
        s  += __shfl_xor(s, off);
        sq += __shfl_xor(sq, off);
    }
    __shared__ float red[8];
    const int wave = tid >> 6, lane = tid & 63;
    if (lane == 0) { red[wave * 2] = s; red[wave * 2 + 1] = sq; }
    __syncthreads();
    s  = red[0] + red[2] + red[4] + red[6];
    sq = red[1] + red[3] + red[5] + red[7];
    const float mu  = s * (1.0f / DM);
    const float var = sq * (1.0f / DM) - mu * mu;
    const float rs  = rsqrtf(var + 1e-5f);
    const float4 gv = ((const float4*)gamma)[tid];
    const float4 bv = ((const float4*)beta)[tid];
    bf16x4 o;
    o[0] = (__bf16)((v.x - mu) * rs * gv.x + bv.x);
    o[1] = (__bf16)((v.y - mu) * rs * gv.y + bv.y);
    o[2] = (__bf16)((v.z - mu) * rs * gv.z + bv.z);
    o[3] = (__bf16)((v.w - mu) * rs * gv.w + bv.w);
    *(bf16x4*)(out + (size_t)row * DM + tid * 4) = o;
}

// ---------------------------------------------------------------------------
// Residual add + LayerNorm: Hres = X + O (f32 out), Hr = LN(Hres) (bf16 out)
// ---------------------------------------------------------------------------
__global__ __launch_bounds__(256) void resid_ln(
    const float* __restrict__ X, const __bf16* __restrict__ O,
    const float* __restrict__ gamma, const float* __restrict__ beta,
    float* __restrict__ Hres, __bf16* __restrict__ Hr)
{
    const int row = blockIdx.x;
    const int tid = threadIdx.x;
    const float4 xv = ((const float4*)(X + (size_t)row * DM))[tid];
    const bf16x4 ov = *(const bf16x4*)(O + (size_t)row * DM + tid * 4);
    float4 v;
    v.x = xv.x + (float)ov[0];
    v.y = xv.y + (float)ov[1];
    v.z = xv.z + (float)ov[2];
    v.w = xv.w + (float)ov[3];
    ((float4*)(Hres + (size_t)row * DM))[tid] = v;

    float s  = v.x + v.y + v.z + v.w;
    float sq = v.x * v.x + v.y * v.y + v.z * v.z + v.w * v.w;
    for (int off = 1; off < 64; off <<= 1) {
        s  += __shfl_xor(s, off);
        sq += __shfl_xor(sq, off);
    }
    __shared__ float red[8];
    const int wave = tid >> 6, lane = tid & 63;
    if (lane == 0) { red[wave * 2] = s; red[wave * 2 + 1] = sq; }
    __syncthreads();
    s  = red[0] + red[2] + red[4] + red[6];
    sq = red[1] + red[3] + red[5] + red[7];
    const float mu  = s * (1.0f / DM);
    const float var = sq * (1.0f / DM) - mu * mu;
    const float rs  = rsqrtf(var + 1e-5f);
    const float4 gv = ((const float4*)gamma)[tid];
    const float4 bv = ((const float4*)beta)[tid];
    bf16x4 o;
    o[0] = (__bf16)((v.x - mu) * rs * gv.x + bv.x);
    o[1] = (__bf16)((v.y - mu) * rs * gv.y + bv.y);
    o[2] = (__bf16)((v.z - mu) * rs * gv.z + bv.z);
    o[3] = (__bf16)((v.w - mu) * rs * gv.w + bv.w);
    *(bf16x4*)(Hr + (size_t)row * DM + tid * 4) = o;
}

// ---------------------------------------------------------------------------
// Transpose f32 [R][C] -> bf16 [C][R].  Block (32,8), grid (C/32, R/32).
// ---------------------------------------------------------------------------
__global__ __launch_bounds__(256) void transpose_f32_bf16(
    const float* __restrict__ in, __bf16* __restrict__ out, int R, int C)
{
    __shared__ float tile[32][33];
    const int c0 = blockIdx.x * 32, r0 = blockIdx.y * 32;
    const int tx = threadIdx.x, ty = threadIdx.y;
#pragma unroll
    for (int i = 0; i < 4; i++)
        tile[ty + i * 8][tx] = in[(size_t)(r0 + ty + i * 8) * C + c0 + tx];
    __syncthreads();
#pragma unroll
    for (int i = 0; i < 4; i++)
        out[(size_t)(c0 + ty + i * 8) * R + r0 + tx] = (__bf16)tile[tx][ty + i * 8];
}

// ---------------------------------------------------------------------------
// Fill null-K row (kv==2048) with null_k, and zero Vt pad columns [2048,2056)
// ---------------------------------------------------------------------------
__global__ __launch_bounds__(256) void fill_null(
    const float* __restrict__ null_k, __bf16* __restrict__ Kb,
    __bf16* __restrict__ Vt)
{
    const int i = blockIdx.x * 256 + threadIdx.x;
    if (i < BATCH * DM) {
        const int b = i >> 10, d = i & (DM - 1);
        Kb[((size_t)b * NKV1 + NKVS) * DM + d] = (__bf16)null_k[d];
    }
    if (i < BATCH * NH * DHD * 8) {  // 16384
        const int bhd = i >> 3, kvp = i & 7;
        Vt[(size_t)bhd * 2056 + 2048 + kvp] = (__bf16)0.0f;
    }
}

// ---------------------------------------------------------------------------
// GEMM  C = A @ Bt^T + bias   (A: [M][K] bf16, Bt: [N][K] bf16)
// 128x128 tile, BK=32, 256 threads (4 waves, 64x64 each), mfma 16x16x32 bf16.
// MODE 0: bf16 flat [M][N]
// MODE 1: bf16 row-padded (K): out row = r + r/2048  (2049 rows per batch)
// MODE 2: bf16 V^T layout: [B][H][64][2056], kv from row, d from col
// MODE 3: f32 out with += resid
// ACT 1: exact GELU
// ---------------------------------------------------------------------------
template<int MODE, int ACT>
__global__ __launch_bounds__(256) void gemm_bt(
    const __bf16* __restrict__ A, const __bf16* __restrict__ Bt,
    const float* __restrict__ bias, void* __restrict__ outp,
    const float* __restrict__ resid, int M, int N, int K)
{
    __shared__ __bf16 As[128][32];
    __shared__ __bf16 Bs[128][32];
    const int tid  = threadIdx.x;
    const int lane = tid & 63, wave = tid >> 6;
    const int g = lane >> 4, c = lane & 15;
    const int m0 = blockIdx.y * 128, n0 = blockIdx.x * 128;
    const int wm = (wave >> 1) * 64, wn = (wave & 1) * 64;

    floatx4 acc[4][4] = {};

    const int srow = tid >> 2;
    const int schk = (tid & 3) * 8;
    const __bf16* Ag = A  + (size_t)(m0 + srow) * K + schk;
    const __bf16* Bg = Bt + (size_t)(n0 + srow) * K + schk;

    for (int k0 = 0; k0 < K; k0 += 32) {
        __syncthreads();
        *(uint4*)&As[srow][schk]      = *(const uint4*)(Ag + k0);
        *(uint4*)&As[srow + 64][schk] = *(const uint4*)(Ag + (size_t)64 * K + k0);
        *(uint4*)&Bs[srow][schk]      = *(const uint4*)(Bg + k0);
        *(uint4*)&Bs[srow + 64][schk] = *(const uint4*)(Bg + (size_t)64 * K + k0);
        __syncthreads();
        bf16x8 af[4], bfr[4];
#pragma unroll
        for (int i = 0; i < 4; i++) af[i]  = *(const bf16x8*)&As[wm + i * 16 + c][g * 8];
#pragma unroll
        for (int j = 0; j < 4; j++) bfr[j] = *(const bf16x8*)&Bs[wn + j * 16 + c][g * 8];
#pragma unroll
        for (int i = 0; i < 4; i++)
#pragma unroll
            for (int j = 0; j < 4; j++)
                acc[i][j] = __builtin_amdgcn_mfma_f32_16x16x32_bf16(af[i], bfr[j], acc[i][j], 0, 0, 0);
    }

    __bf16* obf = (__bf16*)outp;
    float*  of  = (float*)outp;
#pragma unroll
    for (int i = 0; i < 4; i++) {
#pragma unroll
        for (int j = 0; j < 4; j++) {
            const int row = m0 + wm + i * 16 + g * 4;
            const int col = n0 + wn + j * 16 + c;
            const float bb = bias[col];
            float xs[4];
#pragma unroll
            for (int r = 0; r < 4; r++) {
                float x = acc[i][j][r] + bb;
                if (ACT == 1) x = 0.5f * x * (1.0f + erff(x * 0.70710678118654752f));
                xs[r] = x;
            }
            if (MODE == 0) {
#pragma unroll
                for (int r = 0; r < 4; r++)
                    obf[(size_t)(row + r) * N + col] = (__bf16)xs[r];
            } else if (MODE == 1) {
#pragma unroll
                for (int r = 0; r < 4; r++) {
                    const int rr = row + r;
                    obf[(size_t)(rr + (rr >> 11)) * N + col] = (__bf16)xs[r];
                }
            } else if (MODE == 2) {
                const int b  = row >> 11;
                const int kv = row & 2047;
                const size_t base =
                    ((size_t)((b * NH + (col >> 6)) * DHD + (col & 63))) * 2056 + kv;
                bf16x4 pk;
                pk[0] = (__bf16)xs[0]; pk[1] = (__bf16)xs[1];
                pk[2] = (__bf16)xs[2]; pk[3] = (__bf16)xs[3];
                *(bf16x4*)(obf + base) = pk;
            } else {
#pragma unroll
                for (int r = 0; r < 4; r++) {
                    const size_t idx = (size_t)(row + r) * N + col;
                    of[idx] = xs[r] + resid[idx];
                }
            }
        }
    }
}

// ---------------------------------------------------------------------------
// Flash attention.  grid (NQ/128, H, B), 256 threads (4 waves).
// Wave w: q rows [qt*128 + w*32, +32).  KV tile = 64.  scale = 1/32.
// Q: [B*NQ][DM] bf16;  Kb: [B][2049][DM] bf16;  Vt: [B][H][64][2056] bf16.
// O: [B*NQ][DM] bf16.
// ---------------------------------------------------------------------------
__global__ __launch_bounds__(256) void attn_kernel(
    const __bf16* __restrict__ Q, const __bf16* __restrict__ Kb,
    const __bf16* __restrict__ Vt, __bf16* __restrict__ O)
{
    __shared__ __bf16 Ks[64][72];
    __shared__ __bf16 Vs[64][72];
    __shared__ __bf16 Ps[4][32][72];

    const int tid = threadIdx.x, lane = tid & 63, w = tid >> 6;
    const int g = lane >> 4, c = lane & 15;
    const int qt = blockIdx.x, h = blockIdx.y, b = blockIdx.z;
    const int q0 = qt * 128 + w * 32;

    // Q fragments (A-operand layout), held in registers for all KV tiles
    bf16x8 qf[2][2];
    const __bf16* Qbase = Q + ((size_t)(b * NQS + q0 + c)) * DM + h * DHD;
#pragma unroll
    for (int mt = 0; mt < 2; mt++)
#pragma unroll
        for (int ks = 0; ks < 2; ks++)
            qf[mt][ks] = *(const bf16x8*)(Qbase + (size_t)mt * 16 * DM + ks * 32 + g * 8);

    float m_i[2][4], l_i[2][4];
    floatx4 oacc[2][4] = {};
#pragma unroll
    for (int mt = 0; mt < 2; mt++)
#pragma unroll
        for (int r = 0; r < 4; r++) { m_i[mt][r] = -1e30f; l_i[mt][r] = 0.0f; }

    // staging indices
    const int kr = tid >> 3, kch = (tid & 7) * 8;   // K: row (0..31), col-chunk (0..56)
    const int vd = tid >> 2, vch = (tid & 3) * 8;   // Vt: d-row (0..63), kv-chunk (0..24)
    const __bf16* Kb_base = Kb + (size_t)b * NKV1 * DM + h * DHD + kch;
    const __bf16* Vt_base = Vt + ((size_t)(b * NH + h) * DHD + vd) * 2056 + vch;
    const uint4 zero4 = make_uint4(0u, 0u, 0u, 0u);

    for (int it = 0; it < 33; it++) {
        const int kv0 = it * 64;
        __syncthreads();
        {
            const int kv1 = kv0 + kr, kv2 = kv0 + kr + 32;
            uint4 ka = (kv1 < NKV1) ? *(const uint4*)(Kb_base + (size_t)kv1 * DM) : zero4;
            uint4 kb2 = (kv2 < NKV1) ? *(const uint4*)(Kb_base + (size_t)kv2 * DM) : zero4;
            *(uint4*)&Ks[kr][kch]      = ka;
            *(uint4*)&Ks[kr + 32][kch] = kb2;
            // V tile: 64 d-rows x 64 kv-cols. Each thread loads TWO uint4s
            // (cols vch and vch+32) -- previously only half the tile was
            // filled, leaving garbage in cols 32..63 -> NaN via PV MFMA.
            uint4 vv0 = (kv0 + vch + 7      < 2056) ? *(const uint4*)(Vt_base + kv0)      : zero4;
            uint4 vv1 = (kv0 + vch + 32 + 7 < 2056) ? *(const uint4*)(Vt_base + kv0 + 32) : zero4;
            *(uint4*)&Vs[vd][vch]      = vv0;
            *(uint4*)&Vs[vd][vch + 32] = vv1;
        }
        __syncthreads();

        // S = Q K^T
        floatx4 s[2][4] = {};
        bf16x8 kf[4][2];
#pragma unroll
        for (int nt = 0; nt < 4; nt++)
#pragma unroll
            for (int ks = 0; ks < 2; ks++)
                kf[nt][ks] = *(const bf16x8*)&Ks[nt * 16 + c][ks * 32 + g * 8];
#pragma unroll
        for (int mt = 0; mt < 2; mt++)
#pragma unroll
            for (int nt = 0; nt < 4; nt++)
#pragma unroll
                for (int ks = 0; ks < 2; ks++)
                    s[mt][nt] = __builtin_amdgcn_mfma_f32_16x16x32_bf16(
                        qf[mt][ks], kf[nt][ks], s[mt][nt], 0, 0, 0);

        // online softmax
#pragma unroll
        for (int mt = 0; mt < 2; mt++) {
            float tmax[4] = {-1e30f, -1e30f, -1e30f, -1e30f};
#pragma unroll
            for (int nt = 0; nt < 4; nt++)
#pragma unroll
                for (int r = 0; r < 4; r++) {
                    const int kv = kv0 + nt * 16 + c;
                    const float sv = (kv < NKV1) ? s[mt][nt][r] * 0.03125f : -1e30f;
                    s[mt][nt][r] = sv;
                    tmax[r] = fmaxf(tmax[r], sv);
                }
#pragma unroll
            for (int r = 0; r < 4; r++) {
                tmax[r] = fmaxf(tmax[r], __shfl_xor(tmax[r], 1));
                tmax[r] = fmaxf(tmax[r], __shfl_xor(tmax[r], 2));
                tmax[r] = fmaxf(tmax[r], __shfl_xor(tmax[r], 4));
                tmax[r] = fmaxf(tmax[r], __shfl_xor(tmax[r], 8));
            }
            float alpha[4], rsum[4];
#pragma unroll
            for (int r = 0; r < 4; r++) {
                const float mn = fmaxf(m_i[mt][r], tmax[r]);
                alpha[r] = __expf(m_i[mt][r] - mn);
                m_i[mt][r] = mn;
                rsum[r] = 0.0f;
            }
#pragma unroll
            for (int nt = 0; nt < 4; nt++)
#pragma unroll
                for (int r = 0; r < 4; r++) {
                    const float p = __expf(s[mt][nt][r] - m_i[mt][r]);
                    rsum[r] += p;
                    Ps[w][mt * 16 + g * 4 + r][nt * 16 + c] = (__bf16)p;
                }
#pragma unroll
            for (int r = 0; r < 4; r++) {
                rsum[r] += __shfl_xor(rsum[r], 1);
                rsum[r] += __shfl_xor(rsum[r], 2);
                rsum[r] += __shfl_xor(rsum[r], 4);
                rsum[r] += __shfl_xor(rsum[r], 8);
                l_i[mt][r] = l_i[mt][r] * alpha[r] + rsum[r];
            }
#pragma unroll
            for (int nt = 0; nt < 4; nt++)
#pragma unroll
                for (int r = 0; r < 4; r++)
                    oacc[mt][nt][r] *= alpha[r];
        }

        // O += P V
        bf16x8 pf[2][2], vf[4][2];
#pragma unroll
        for (int mt = 0; mt < 2; mt++)
#pragma unroll
            for (int ks = 0; ks < 2; ks++)
                pf[mt][ks] = *(const bf16x8*)&Ps[w][mt * 16 + c][ks * 32 + g * 8];
#pragma unroll
        for (int nt = 0; nt < 4; nt++)
#pragma unroll
            for (int ks = 0; ks < 2; ks++)
                vf[nt][ks] = *(const bf16x8*)&Vs[nt * 16 + c][ks * 32 + g * 8];
#pragma unroll
        for (int mt = 0; mt < 2; mt++)
#pragma unroll
            for (int nt = 0; nt < 4; nt++)
#pragma unroll
                for (int ks = 0; ks < 2; ks++)
                    oacc[mt][nt] = __builtin_amdgcn_mfma_f32_16x16x32_bf16(
                        pf[mt][ks], vf[nt][ks], oacc[mt][nt], 0, 0, 0);
    }

    __bf16* Ob = O + ((size_t)(b * NQS + q0)) * DM + h * DHD;
#pragma unroll
    for (int mt = 0; mt < 2; mt++)
#pragma unroll
        for (int nt = 0; nt < 4; nt++)
#pragma unroll
            for (int r = 0; r < 4; r++) {
                const float ov = oacc[mt][nt][r] / l_i[mt][r];
                Ob[(size_t)(mt * 16 + g * 4 + r) * DM + nt * 16 + c] = (__bf16)ov;
            }
}

// ---------------------------------------------------------------------------
extern "C" void kernel_launch(void* const* d_in, const int* in_sizes, int n_in,
                              void* d_out, int out_size, void* d_ws, size_t ws_size,
                              hipStream_t stream)
{
    const float* X      = (const float*)d_in[0];
    const float* Y      = (const float*)d_in[1];
    const float* Wq     = (const float*)d_in[2];
    const float* bq     = (const float*)d_in[3];
    const float* Wk     = (const float*)d_in[4];
    const float* bk     = (const float*)d_in[5];
    const float* Wv     = (const float*)d_in[6];
    const float* bv     = (const float*)d_in[7];
    const float* null_k = (const float*)d_in[8];
    const float* g0     = (const float*)d_in[9];
    const float* b0     = (const float*)d_in[10];
    const float* g0kv   = (const float*)d_in[11];
    const float* b0kv   = (const float*)d_in[12];
    const float* g1     = (const float*)d_in[13];
    const float* b1     = (const float*)d_in[14];
    const float* W1     = (const float*)d_in[15];
    const float* bf1    = (const float*)d_in[16];
    const float* W2     = (const float*)d_in[17];
    const float* bf2    = (const float*)d_in[18];
    float* out = (float*)d_out;

    const int ROWS = BATCH * NQS;  // 4096

    // workspace carve (bytes)
    char* p = (char*)d_ws;
    __bf16* Xn   = (__bf16*)p; p += (size_t)ROWS * DM * 2;            // 8 MB
    __bf16* Yn   = (__bf16*)p; p += (size_t)ROWS * DM * 2;
    __bf16* WqT  = (__bf16*)p; p += (size_t)DM * DM * 2;
    __bf16* WkT  = (__bf16*)p; p += (size_t)DM * DM * 2;
    __bf16* WvT  = (__bf16*)p; p += (size_t)DM * DM * 2;
    __bf16* W1T  = (__bf16*)p; p += (size_t)4 * DM * DM * 2;          // [4096][1024]
    __bf16* W2T  = (__bf16*)p; p += (size_t)4 * DM * DM * 2;          // [1024][4096]
    __bf16* Qbf  = (__bf16*)p; p += (size_t)ROWS * DM * 2;
    __bf16* Kbf  = (__bf16*)p; p += (size_t)BATCH * NKV1 * DM * 2;
    __bf16* Vt   = (__bf16*)p; p += (size_t)BATCH * NH * DHD * 2056 * 2;
    __bf16* Obf  = (__bf16*)p; p += (size_t)ROWS * DM * 2;
    float*  Hres = (float*)p;  p += (size_t)ROWS * DM * 4;
    __bf16* Hr   = (__bf16*)p; p += (size_t)ROWS * DM * 2;
    __bf16* Gbf  = (__bf16*)p; p += (size_t)ROWS * 4 * DM * 2;        // 33.5 MB

    // 1. LayerNorms
    ln_to_bf16<<<ROWS, 256, 0, stream>>>(X, g0, b0, Xn);
    ln_to_bf16<<<ROWS, 256, 0, stream>>>(Y, g0kv, b0kv, Yn);

    // 2. weight transposes (f32 -> bf16, W^T)
    transpose_f32_bf16<<<dim3(DM / 32, DM / 32), dim3(32, 8), 0, stream>>>(Wq, WqT, DM, DM);
    transpose_f32_bf16<<<dim3(DM / 32, DM / 32), dim3(32, 8), 0, stream>>>(Wk, WkT, DM, DM);
    transpose_f32_bf16<<<dim3(DM / 32, DM / 32), dim3(32, 8), 0, stream>>>(Wv, WvT, DM, DM);
    transpose_f32_bf16<<<dim3(4 * DM / 32, DM / 32), dim3(32, 8), 0, stream>>>(W1, W1T, DM, 4 * DM);
    transpose_f32_bf16<<<dim3(DM / 32, 4 * DM / 32), dim3(32, 8), 0, stream>>>(W2, W2T, 4 * DM, DM);

    // 3. Q/K/V projections
    gemm_bt<0, 0><<<dim3(DM / 128, ROWS / 128), 256, 0, stream>>>(
        Xn, WqT, bq, (void*)Qbf, nullptr, ROWS, DM, DM);
    gemm_bt<1, 0><<<dim3(DM / 128, ROWS / 128), 256, 0, stream>>>(
        Yn, WkT, bk, (void*)Kbf, nullptr, ROWS, DM, DM);
    gemm_bt<2, 0><<<dim3(DM / 128, ROWS / 128), 256, 0, stream>>>(
        Yn, WvT, bv, (void*)Vt, nullptr, ROWS, DM, DM);
    fill_null<<<64, 256, 0, stream>>>(null_k, Kbf, Vt);

    // 4. attention
    attn_kernel<<<dim3(NQS / 128, NH, BATCH), 256, 0, stream>>>(Qbf, Kbf, Vt, Obf);

    // 5. residual + LN
    resid_ln<<<ROWS, 256, 0, stream>>>(X, Obf, g1, b1, Hres, Hr);

    // 6. FFN
    gemm_bt<0, 1><<<dim3(4 * DM / 128, ROWS / 128), 256, 0, stream>>>(
        Hr, W1T, bf1, (void*)Gbf, nullptr, ROWS, 4 * DM, DM);
    gemm_bt<3, 0><<<dim3(DM / 128, ROWS / 128), 256, 0, stream>>>(
        Gbf, W2T, bf2, (void*)out, Hres, ROWS, DM, 4 * DM);
}

// Round 3
// 489.836 us; speedup vs baseline: 1.2091x; 1.2091x over previous
//
#include <hip/hip_runtime.h>
#include <hip/hip_bf16.h>
#include <math.h>
#include <stdint.h>

typedef __bf16 bf16x8 __attribute__((ext_vector_type(8)));
typedef __bf16 bf16x4 __attribute__((ext_vector_type(4)));
typedef float floatx4 __attribute__((ext_vector_type(4)));
typedef short shortx4 __attribute__((ext_vector_type(4)));

#define NQS   2048
#define NKVS  2048
#define NKV1  2049
#define DM    1024
#define NH    16
#define DHD   64
#define BATCH 2

// async global->LDS, 16B per lane. LDS dest must be wave-uniform base + lane*16.
__device__ __forceinline__ void gld_lds16(const __bf16* gp, __bf16* lp) {
    __builtin_amdgcn_global_load_lds(
        (const __attribute__((address_space(1))) uint32_t*)(uintptr_t)gp,
        (__attribute__((address_space(3))) uint32_t*)(uintptr_t)lp,
        16, 0, 0);
}

// ---------------------------------------------------------------------------
// LayerNorm (f32 in) -> bf16 out.  One block per row of 1024.
// ---------------------------------------------------------------------------
__global__ __launch_bounds__(256) void ln_to_bf16(
    const float* __restrict__ X, const float* __restrict__ gamma,
    const float* __restrict__ beta, __bf16* __restrict__ out)
{
    const int row = blockIdx.x;
    const int tid = threadIdx.x;
    const float4 v = ((const float4*)(X + (size_t)row * DM))[tid];
    float s  = v.x + v.y + v.z + v.w;
    float sq = v.x * v.x + v.y * v.y + v.z * v.z + v.w * v.w;
    for (int off = 1; off < 64; off <<= 1) {
        s  += __shfl_xor(s, off);
        sq += __shfl_xor(sq, off);
    }
    __shared__ float red[8];
    const int wave = tid >> 6, lane = tid & 63;
    if (lane == 0) { red[wave * 2] = s; red[wave * 2 + 1] = sq; }
    __syncthreads();
    s  = red[0] + red[2] + red[4] + red[6];
    sq = red[1] + red[3] + red[5] + red[7];
    const float mu  = s * (1.0f / DM);
    const float var = sq * (1.0f / DM) - mu * mu;
    const float rs  = rsqrtf(var + 1e-5f);
    const float4 gv = ((const float4*)gamma)[tid];
    const float4 bv = ((const float4*)beta)[tid];
    bf16x4 o;
    o[0] = (__bf16)((v.x - mu) * rs * gv.x + bv.x);
    o[1] = (__bf16)((v.y - mu) * rs * gv.y + bv.y);
    o[2] = (__bf16)((v.z - mu) * rs * gv.z + bv.z);
    o[3] = (__bf16)((v.w - mu) * rs * gv.w + bv.w);
    *(bf16x4*)(out + (size_t)row * DM + tid * 4) = o;
}

// ---------------------------------------------------------------------------
// Residual add + LayerNorm: Hres = X + O (f32 out), Hr = LN(Hres) (bf16 out)
// ---------------------------------------------------------------------------
__global__ __launch_bounds__(256) void resid_ln(
    const float* __restrict__ X, const __bf16* __restrict__ O,
    const float* __restrict__ gamma, const float* __restrict__ beta,
    float* __restrict__ Hres, __bf16* __restrict__ Hr)
{
    const int row = blockIdx.x;
    const int tid = threadIdx.x;
    const float4 xv = ((const float4*)(X + (size_t)row * DM))[tid];
    const bf16x4 ov = *(const bf16x4*)(O + (size_t)row * DM + tid * 4);
    float4 v;
    v.x = xv.x + (float)ov[0];
    v.y = xv.y + (float)ov[1];
    v.z = xv.z + (float)ov[2];
    v.w = xv.w + (float)ov[3];
    ((float4*)(Hres + (size_t)row * DM))[tid] = v;

    float s  = v.x + v.y + v.z + v.w;
    float sq = v.x * v.x + v.y * v.y + v.z * v.z + v.w * v.w;
    for (int off = 1; off < 64; off <<= 1) {
        s  += __shfl_xor(s, off);
        sq += __shfl_xor(sq, off);
    }
    __shared__ float red[8];
    const int wave = tid >> 6, lane = tid & 63;
    if (lane == 0) { red[wave * 2] = s; red[wave * 2 + 1] = sq; }
    __syncthreads();
    s  = red[0] + red[2] + red[4] + red[6];
    sq = red[1] + red[3] + red[5] + red[7];
    const float mu  = s * (1.0f / DM);
    const float var = sq * (1.0f / DM) - mu * mu;
    const float rs  = rsqrtf(var + 1e-5f);
    const float4 gv = ((const float4*)gamma)[tid];
    const float4 bv = ((const float4*)beta)[tid];
    bf16x4 o;
    o[0] = (__bf16)((v.x - mu) * rs * gv.x + bv.x);
    o[1] = (__bf16)((v.y - mu) * rs * gv.y + bv.y);
    o[2] = (__bf16)((v.z - mu) * rs * gv.z + bv.z);
    o[3] = (__bf16)((v.w - mu) * rs * gv.w + bv.w);
    *(bf16x4*)(Hr + (size_t)row * DM + tid * 4) = o;
}

// ---------------------------------------------------------------------------
// Transpose f32 [R][C] -> bf16 [C][R].  Block (32,8), grid (C/32, R/32).
// ---------------------------------------------------------------------------
__global__ __launch_bounds__(256) void transpose_f32_bf16(
    const float* __restrict__ in, __bf16* __restrict__ out, int R, int C)
{
    __shared__ float tile[32][33];
    const int c0 = blockIdx.x * 32, r0 = blockIdx.y * 32;
    const int tx = threadIdx.x, ty = threadIdx.y;
#pragma unroll
    for (int i = 0; i < 4; i++)
        tile[ty + i * 8][tx] = in[(size_t)(r0 + ty + i * 8) * C + c0 + tx];
    __syncthreads();
#pragma unroll
    for (int i = 0; i < 4; i++)
        out[(size_t)(c0 + ty + i * 8) * R + r0 + tx] = (__bf16)tile[tx][ty + i * 8];
}

// ---------------------------------------------------------------------------
// Fill null-K row (kv==2048) with null_k, and zero Vt pad columns [2048,2056)
// ---------------------------------------------------------------------------
__global__ __launch_bounds__(256) void fill_null(
    const float* __restrict__ null_k, __bf16* __restrict__ Kb,
    __bf16* __restrict__ Vt)
{
    const int i = blockIdx.x * 256 + threadIdx.x;
    if (i < BATCH * DM) {
        const int b = i >> 10, d = i & (DM - 1);
        Kb[((size_t)b * NKV1 + NKVS) * DM + d] = (__bf16)null_k[d];
    }
    if (i < BATCH * NH * DHD * 8) {  // 16384
        const int bhd = i >> 3, kvp = i & 7;
        Vt[(size_t)bhd * 2056 + 2048 + kvp] = (__bf16)0.0f;
    }
}

// ---------------------------------------------------------------------------
// GEMM  C = A @ Bt^T + bias   (A: [M][K] bf16, Bt: [N][K] bf16)
// 128x128 tile, BK=32, 256 threads (4 waves, 64x64 each), mfma 16x16x32 bf16.
// Staging via global_load_lds width=16 (LDS layout = tid*16 bytes, unpadded).
// MODE 0: bf16 flat [M][N]
// MODE 1: bf16 row-padded (K): out row = r + r/2048  (2049 rows per batch)
// MODE 2: bf16 V^T layout: [B][H][64][2056], kv from row, d from col
// MODE 3: f32 out with += resid
// ACT 1: exact GELU
// ---------------------------------------------------------------------------
template<int MODE, int ACT>
__global__ __launch_bounds__(256) void gemm_bt(
    const __bf16* __restrict__ A, const __bf16* __restrict__ Bt,
    const float* __restrict__ bias, void* __restrict__ outp,
    const float* __restrict__ resid, int M, int N, int K)
{
    __shared__ __bf16 As[128][32];
    __shared__ __bf16 Bs[128][32];
    const int tid  = threadIdx.x;
    const int lane = tid & 63, wave = tid >> 6;
    const int g = lane >> 4, c = lane & 15;
    const int m0 = blockIdx.y * 128, n0 = blockIdx.x * 128;
    const int wm = (wave >> 1) * 64, wn = (wave & 1) * 64;

    floatx4 acc[4][4] = {};

    const int srow = tid >> 2;
    const int schk = (tid & 3) * 8;
    const __bf16* Ag = A  + (size_t)(m0 + srow) * K + schk;
    const __bf16* Bg = Bt + (size_t)(n0 + srow) * K + schk;
    __bf16* lA0 = &As[srow][schk];
    __bf16* lA1 = &As[srow + 64][schk];
    __bf16* lB0 = &Bs[srow][schk];
    __bf16* lB1 = &Bs[srow + 64][schk];

    for (int k0 = 0; k0 < K; k0 += 32) {
        __syncthreads();
        gld_lds16(Ag + k0, lA0);
        gld_lds16(Ag + (size_t)64 * K + k0, lA1);
        gld_lds16(Bg + k0, lB0);
        gld_lds16(Bg + (size_t)64 * K + k0, lB1);
        __syncthreads();
        bf16x8 af[4], bfr[4];
#pragma unroll
        for (int i = 0; i < 4; i++) af[i]  = *(const bf16x8*)&As[wm + i * 16 + c][g * 8];
#pragma unroll
        for (int j = 0; j < 4; j++) bfr[j] = *(const bf16x8*)&Bs[wn + j * 16 + c][g * 8];
#pragma unroll
        for (int i = 0; i < 4; i++)
#pragma unroll
            for (int j = 0; j < 4; j++)
                acc[i][j] = __builtin_amdgcn_mfma_f32_16x16x32_bf16(af[i], bfr[j], acc[i][j], 0, 0, 0);
    }

    __bf16* obf = (__bf16*)outp;
    float*  of  = (float*)outp;
#pragma unroll
    for (int i = 0; i < 4; i++) {
#pragma unroll
        for (int j = 0; j < 4; j++) {
            const int row = m0 + wm + i * 16 + g * 4;
            const int col = n0 + wn + j * 16 + c;
            const float bb = bias[col];
            float xs[4];
#pragma unroll
            for (int r = 0; r < 4; r++) {
                float x = acc[i][j][r] + bb;
                if (ACT == 1) x = 0.5f * x * (1.0f + erff(x * 0.70710678118654752f));
                xs[r] = x;
            }
            if (MODE == 0) {
#pragma unroll
                for (int r = 0; r < 4; r++)
                    obf[(size_t)(row + r) * N + col] = (__bf16)xs[r];
            } else if (MODE == 1) {
#pragma unroll
                for (int r = 0; r < 4; r++) {
                    const int rr = row + r;
                    obf[(size_t)(rr + (rr >> 11)) * N + col] = (__bf16)xs[r];
                }
            } else if (MODE == 2) {
                const int b  = row >> 11;
                const int kv = row & 2047;
                const size_t base =
                    ((size_t)((b * NH + (col >> 6)) * DHD + (col & 63))) * 2056 + kv;
                bf16x4 pk;
                pk[0] = (__bf16)xs[0]; pk[1] = (__bf16)xs[1];
                pk[2] = (__bf16)xs[2]; pk[3] = (__bf16)xs[3];
                *(bf16x4*)(obf + base) = pk;
            } else {
#pragma unroll
                for (int r = 0; r < 4; r++) {
                    const size_t idx = (size_t)(row + r) * N + col;
                    of[idx] = xs[r] + resid[idx];
                }
            }
        }
    }
}

// ---------------------------------------------------------------------------
// Flash attention, S^T formulation.  grid (NQ/64, H, B), 256 threads (4 waves).
// Wave w handles q rows [qb*64 + w*16, +16).  KV tile = 64.  scale = 1/32.
// S^T = K·Q^T  (mfma 16x16x32: C cols = q = lane&15, rows = kv = g*4+reg)
//  -> softmax reduction over kv = in-register + 2 shuffles (xor 16, 32)
//  -> P^T sits in regs in EXACTLY the B-operand layout of mfma 16x16x16
// O^T = V^T·P^T (mfma 16x16x16: A = V^T frags from Vs, no P LDS round-trip)
// ---------------------------------------------------------------------------
__global__ __launch_bounds__(256, 4) void attn_kernel(
    const __bf16* __restrict__ Q, const __bf16* __restrict__ Kb,
    const __bf16* __restrict__ Vt, __bf16* __restrict__ O)
{
    __shared__ __bf16 Ks[64][72];
    __shared__ __bf16 Vs[64][72];

    const int tid = threadIdx.x, lane = tid & 63, w = tid >> 6;
    const int g = lane >> 4, c = lane & 15;
    const int h = blockIdx.y, b = blockIdx.z;
    const int q0w = blockIdx.x * 64 + w * 16;

    // Q fragments (B-operand: n = q = c, k-chunk = g*8), kept in registers
    bf16x8 qf[2];
    const __bf16* Qbase = Q + ((size_t)(b * NQS + q0w + c)) * DM + h * DHD;
    qf[0] = *(const bf16x8*)(Qbase + g * 8);
    qf[1] = *(const bf16x8*)(Qbase + 32 + g * 8);

    float m_i = -1e30f, l_i = 0.0f;
    floatx4 oacc[4] = {};

    const int kr = tid >> 3, kch = (tid & 7) * 8;   // K staging
    const int vd = tid >> 2, vch = (tid & 3) * 8;   // V^T staging
    const __bf16* Kb_base = Kb + (size_t)b * NKV1 * DM + h * DHD + kch;
    const __bf16* Vt_base = Vt + ((size_t)(b * NH + h) * DHD + vd) * 2056 + vch;
    const uint4 zero4 = make_uint4(0u, 0u, 0u, 0u);

    for (int it = 0; it < 33; it++) {
        const int kv0 = it * 64;
        __syncthreads();
        {
            const int kv1 = kv0 + kr, kv2 = kv1 + 32;
            uint4 ka  = (kv1 < NKV1) ? *(const uint4*)(Kb_base + (size_t)kv1 * DM) : zero4;
            uint4 kb2 = (kv2 < NKV1) ? *(const uint4*)(Kb_base + (size_t)kv2 * DM) : zero4;
            *(uint4*)&Ks[kr][kch]      = ka;
            *(uint4*)&Ks[kr + 32][kch] = kb2;
            uint4 vv0 = (kv0 + vch + 7  < 2056) ? *(const uint4*)(Vt_base + kv0)      : zero4;
            uint4 vv1 = (kv0 + vch + 39 < 2056) ? *(const uint4*)(Vt_base + kv0 + 32) : zero4;
            *(uint4*)&Vs[vd][vch]      = vv0;
            *(uint4*)&Vs[vd][vch + 32] = vv1;
        }
        __syncthreads();

        // S^T = K Q^T : A = K frag (m = kv), B = Q frag (n = q)
        floatx4 s[4] = {};
        bf16x8 kf[4][2];
#pragma unroll
        for (int kvt = 0; kvt < 4; kvt++) {
            kf[kvt][0] = *(const bf16x8*)&Ks[kvt * 16 + c][g * 8];
            kf[kvt][1] = *(const bf16x8*)&Ks[kvt * 16 + c][32 + g * 8];
        }
#pragma unroll
        for (int kvt = 0; kvt < 4; kvt++) {
            s[kvt] = __builtin_amdgcn_mfma_f32_16x16x32_bf16(kf[kvt][0], qf[0], s[kvt], 0, 0, 0);
            s[kvt] = __builtin_amdgcn_mfma_f32_16x16x32_bf16(kf[kvt][1], qf[1], s[kvt], 0, 0, 0);
        }

#pragma unroll
        for (int kvt = 0; kvt < 4; kvt++)
#pragma unroll
            for (int r = 0; r < 4; r++)
                s[kvt][r] *= 0.03125f;
        if (kv0 + 64 > NKV1) {   // only the last tile is partial
#pragma unroll
            for (int kvt = 0; kvt < 4; kvt++)
#pragma unroll
                for (int r = 0; r < 4; r++)
                    if (kv0 + kvt * 16 + g * 4 + r >= NKV1) s[kvt][r] = -1e30f;
        }

        // per-q max over this tile's 64 kv: 16 in-register + 2 shuffles
        float t0 = fmaxf(fmaxf(s[0][0], s[0][1]), fmaxf(s[0][2], s[0][3]));
        float t1 = fmaxf(fmaxf(s[1][0], s[1][1]), fmaxf(s[1][2], s[1][3]));
        float t2 = fmaxf(fmaxf(s[2][0], s[2][1]), fmaxf(s[2][2], s[2][3]));
        float t3 = fmaxf(fmaxf(s[3][0], s[3][1]), fmaxf(s[3][2], s[3][3]));
        float tmax = fmaxf(fmaxf(t0, t1), fmaxf(t2, t3));
        tmax = fmaxf(tmax, __shfl_xor(tmax, 16));
        tmax = fmaxf(tmax, __shfl_xor(tmax, 32));

        const float mn = fmaxf(m_i, tmax);
        const float alpha = __expf(m_i - mn);
        m_i = mn;

        float rsum = 0.0f;
        shortx4 pf[4];
#pragma unroll
        for (int kvt = 0; kvt < 4; kvt++) {
            bf16x4 pb;
#pragma unroll
            for (int r = 0; r < 4; r++) {
                const float p = __expf(s[kvt][r] - mn);
                rsum += p;
                pb[r] = (__bf16)p;
            }
            pf[kvt] = __builtin_bit_cast(shortx4, pb);
        }
        rsum += __shfl_xor(rsum, 16);
        rsum += __shfl_xor(rsum, 32);
        l_i = l_i * alpha + rsum;

#pragma unroll
        for (int dt = 0; dt < 4; dt++)
#pragma unroll
            for (int r = 0; r < 4; r++)
                oacc[dt][r] *= alpha;

        // O^T += V^T P^T : A = V^T frag (m = d, k = kv = g*4+j), B = P^T (in regs)
#pragma unroll
        for (int kvt = 0; kvt < 4; kvt++) {
            shortx4 vfr[4];
#pragma unroll
            for (int dt = 0; dt < 4; dt++)
                vfr[dt] = *(const shortx4*)&Vs[dt * 16 + c][kvt * 16 + g * 4];
#pragma unroll
            for (int dt = 0; dt < 4; dt++)
                oacc[dt] = __builtin_amdgcn_mfma_f32_16x16x16bf16_1k(
                    vfr[dt], pf[kvt], oacc[dt], 0, 0, 0);
        }
    }

    const float inv_l = 1.0f / l_i;
    __bf16* Ob = O + ((size_t)(b * NQS + q0w + c)) * DM + h * DHD;
#pragma unroll
    for (int dt = 0; dt < 4; dt++) {
        bf16x4 ob;
#pragma unroll
        for (int r = 0; r < 4; r++) ob[r] = (__bf16)(oacc[dt][r] * inv_l);
        *(bf16x4*)(Ob + dt * 16 + g * 4) = ob;
    }
}

// ---------------------------------------------------------------------------
extern "C" void kernel_launch(void* const* d_in, const int* in_sizes, int n_in,
                              void* d_out, int out_size, void* d_ws, size_t ws_size,
                              hipStream_t stream)
{
    const float* X      = (const float*)d_in[0];
    const float* Y      = (const float*)d_in[1];
    const float* Wq     = (const float*)d_in[2];
    const float* bq     = (const float*)d_in[3];
    const float* Wk     = (const float*)d_in[4];
    const float* bk     = (const float*)d_in[5];
    const float* Wv     = (const float*)d_in[6];
    const float* bv     = (const float*)d_in[7];
    const float* null_k = (const float*)d_in[8];
    const float* g0     = (const float*)d_in[9];
    const float* b0     = (const float*)d_in[10];
    const float* g0kv   = (const float*)d_in[11];
    const float* b0kv   = (const float*)d_in[12];
    const float* g1     = (const float*)d_in[13];
    const float* b1     = (const float*)d_in[14];
    const float* W1     = (const float*)d_in[15];
    const float* bf1    = (const float*)d_in[16];
    const float* W2     = (const float*)d_in[17];
    const float* bf2    = (const float*)d_in[18];
    float* out = (float*)d_out;

    const int ROWS = BATCH * NQS;  // 4096

    // workspace carve (bytes)
    char* p = (char*)d_ws;
    __bf16* Xn   = (__bf16*)p; p += (size_t)ROWS * DM * 2;
    __bf16* Yn   = (__bf16*)p; p += (size_t)ROWS * DM * 2;
    __bf16* WqT  = (__bf16*)p; p += (size_t)DM * DM * 2;
    __bf16* WkT  = (__bf16*)p; p += (size_t)DM * DM * 2;
    __bf16* WvT  = (__bf16*)p; p += (size_t)DM * DM * 2;
    __bf16* W1T  = (__bf16*)p; p += (size_t)4 * DM * DM * 2;
    __bf16* W2T  = (__bf16*)p; p += (size_t)4 * DM * DM * 2;
    __bf16* Qbf  = (__bf16*)p; p += (size_t)ROWS * DM * 2;
    __bf16* Kbf  = (__bf16*)p; p += (size_t)BATCH * NKV1 * DM * 2;
    __bf16* Vt   = (__bf16*)p; p += (size_t)BATCH * NH * DHD * 2056 * 2;
    __bf16* Obf  = (__bf16*)p; p += (size_t)ROWS * DM * 2;
    float*  Hres = (float*)p;  p += (size_t)ROWS * DM * 4;
    __bf16* Hr   = (__bf16*)p; p += (size_t)ROWS * DM * 2;
    __bf16* Gbf  = (__bf16*)p; p += (size_t)ROWS * 4 * DM * 2;

    // 1. LayerNorms
    ln_to_bf16<<<ROWS, 256, 0, stream>>>(X, g0, b0, Xn);
    ln_to_bf16<<<ROWS, 256, 0, stream>>>(Y, g0kv, b0kv, Yn);

    // 2. weight transposes (f32 -> bf16, W^T)
    transpose_f32_bf16<<<dim3(DM / 32, DM / 32), dim3(32, 8), 0, stream>>>(Wq, WqT, DM, DM);
    transpose_f32_bf16<<<dim3(DM / 32, DM / 32), dim3(32, 8), 0, stream>>>(Wk, WkT, DM, DM);
    transpose_f32_bf16<<<dim3(DM / 32, DM / 32), dim3(32, 8), 0, stream>>>(Wv, WvT, DM, DM);
    transpose_f32_bf16<<<dim3(4 * DM / 32, DM / 32), dim3(32, 8), 0, stream>>>(W1, W1T, DM, 4 * DM);
    transpose_f32_bf16<<<dim3(DM / 32, 4 * DM / 32), dim3(32, 8), 0, stream>>>(W2, W2T, 4 * DM, DM);

    // 3. Q/K/V projections
    gemm_bt<0, 0><<<dim3(DM / 128, ROWS / 128), 256, 0, stream>>>(
        Xn, WqT, bq, (void*)Qbf, nullptr, ROWS, DM, DM);
    gemm_bt<1, 0><<<dim3(DM / 128, ROWS / 128), 256, 0, stream>>>(
        Yn, WkT, bk, (void*)Kbf, nullptr, ROWS, DM, DM);
    gemm_bt<2, 0><<<dim3(DM / 128, ROWS / 128), 256, 0, stream>>>(
        Yn, WvT, bv, (void*)Vt, nullptr, ROWS, DM, DM);
    fill_null<<<64, 256, 0, stream>>>(null_k, Kbf, Vt);

    // 4. attention
    attn_kernel<<<dim3(NQS / 64, NH, BATCH), 256, 0, stream>>>(Qbf, Kbf, Vt, Obf);

    // 5. residual + LN
    resid_ln<<<ROWS, 256, 0, stream>>>(X, Obf, g1, b1, Hres, Hr);

    // 6. FFN
    gemm_bt<0, 1><<<dim3(4 * DM / 128, ROWS / 128), 256, 0, stream>>>(
        Hr, W1T, bf1, (void*)Gbf, nullptr, ROWS, 4 * DM, DM);
    gemm_bt<3, 0><<<dim3(DM / 128, ROWS / 128), 256, 0, stream>>>(
        Gbf, W2T, bf2, (void*)out, Hres, ROWS, DM, 4 * DM);
}

// Round 4
// 437.769 us; speedup vs baseline: 1.3529x; 1.1189x over previous
//
#include <hip/hip_runtime.h>
#include <hip/hip_bf16.h>
#include <math.h>
#include <stdint.h>

typedef __bf16 bf16x8 __attribute__((ext_vector_type(8)));
typedef __bf16 bf16x4 __attribute__((ext_vector_type(4)));
typedef float floatx4 __attribute__((ext_vector_type(4)));
typedef short shortx4 __attribute__((ext_vector_type(4)));

#define NQS   2048
#define NKVS  2048
#define NKV1  2049
#define DM    1024
#define NH    16
#define DHD   64
#define BATCH 2
#define ROWS  (BATCH * NQS)   // 4096

// async global->LDS, 16B per lane. LDS dest must be wave-uniform base + lane*16.
__device__ __forceinline__ void gld_lds16(const __bf16* gp, __bf16* lp) {
    __builtin_amdgcn_global_load_lds(
        (const __attribute__((address_space(1))) uint32_t*)(uintptr_t)gp,
        (__attribute__((address_space(3))) uint32_t*)(uintptr_t)lp,
        16, 0, 0);
}

// ---------------------------------------------------------------------------
// LayerNorm (f32 in) -> bf16 out.  One block per row of 1024.
// ---------------------------------------------------------------------------
__global__ __launch_bounds__(256) void ln_to_bf16(
    const float* __restrict__ X, const float* __restrict__ gamma,
    const float* __restrict__ beta, __bf16* __restrict__ out)
{
    const int row = blockIdx.x;
    const int tid = threadIdx.x;
    const float4 v = ((const float4*)(X + (size_t)row * DM))[tid];
    float s  = v.x + v.y + v.z + v.w;
    float sq = v.x * v.x + v.y * v.y + v.z * v.z + v.w * v.w;
    for (int off = 1; off < 64; off <<= 1) {
        s  += __shfl_xor(s, off);
        sq += __shfl_xor(sq, off);
    }
    __shared__ float red[8];
    const int wave = tid >> 6, lane = tid & 63;
    if (lane == 0) { red[wave * 2] = s; red[wave * 2 + 1] = sq; }
    __syncthreads();
    s  = red[0] + red[2] + red[4] + red[6];
    sq = red[1] + red[3] + red[5] + red[7];
    const float mu  = s * (1.0f / DM);
    const float var = sq * (1.0f / DM) - mu * mu;
    const float rs  = rsqrtf(var + 1e-5f);
    const float4 gv = ((const float4*)gamma)[tid];
    const float4 bv = ((const float4*)beta)[tid];
    bf16x4 o;
    o[0] = (__bf16)((v.x - mu) * rs * gv.x + bv.x);
    o[1] = (__bf16)((v.y - mu) * rs * gv.y + bv.y);
    o[2] = (__bf16)((v.z - mu) * rs * gv.z + bv.z);
    o[3] = (__bf16)((v.w - mu) * rs * gv.w + bv.w);
    *(bf16x4*)(out + (size_t)row * DM + tid * 4) = o;
}

// ---------------------------------------------------------------------------
// Residual add + LayerNorm: Hres = X + O (f32 out), Hr = LN(Hres) (bf16 out)
// ---------------------------------------------------------------------------
__global__ __launch_bounds__(256) void resid_ln(
    const float* __restrict__ X, const __bf16* __restrict__ O,
    const float* __restrict__ gamma, const float* __restrict__ beta,
    float* __restrict__ Hres, __bf16* __restrict__ Hr)
{
    const int row = blockIdx.x;
    const int tid = threadIdx.x;
    const float4 xv = ((const float4*)(X + (size_t)row * DM))[tid];
    const bf16x4 ov = *(const bf16x4*)(O + (size_t)row * DM + tid * 4);
    float4 v;
    v.x = xv.x + (float)ov[0];
    v.y = xv.y + (float)ov[1];
    v.z = xv.z + (float)ov[2];
    v.w = xv.w + (float)ov[3];
    ((float4*)(Hres + (size_t)row * DM))[tid] = v;

    float s  = v.x + v.y + v.z + v.w;
    float sq = v.x * v.x + v.y * v.y + v.z * v.z + v.w * v.w;
    for (int off = 1; off < 64; off <<= 1) {
        s  += __shfl_xor(s, off);
        sq += __shfl_xor(sq, off);
    }
    __shared__ float red[8];
    const int wave = tid >> 6, lane = tid & 63;
    if (lane == 0) { red[wave * 2] = s; red[wave * 2 + 1] = sq; }
    __syncthreads();
    s  = red[0] + red[2] + red[4] + red[6];
    sq = red[1] + red[3] + red[5] + red[7];
    const float mu  = s * (1.0f / DM);
    const float var = sq * (1.0f / DM) - mu * mu;
    const float rs  = rsqrtf(var + 1e-5f);
    const float4 gv = ((const float4*)gamma)[tid];
    const float4 bv = ((const float4*)beta)[tid];
    bf16x4 o;
    o[0] = (__bf16)((v.x - mu) * rs * gv.x + bv.x);
    o[1] = (__bf16)((v.y - mu) * rs * gv.y + bv.y);
    o[2] = (__bf16)((v.z - mu) * rs * gv.z + bv.z);
    o[3] = (__bf16)((v.w - mu) * rs * gv.w + bv.w);
    *(bf16x4*)(Hr + (size_t)row * DM + tid * 4) = o;
}

// ---------------------------------------------------------------------------
// Transpose f32 [R][C] -> bf16 [C][R].  Block (32,8), grid (C/32, R/32).
// ---------------------------------------------------------------------------
__global__ __launch_bounds__(256) void transpose_f32_bf16(
    const float* __restrict__ in, __bf16* __restrict__ out, int R, int C)
{
    __shared__ float tile[32][33];
    const int c0 = blockIdx.x * 32, r0 = blockIdx.y * 32;
    const int tx = threadIdx.x, ty = threadIdx.y;
#pragma unroll
    for (int i = 0; i < 4; i++)
        tile[ty + i * 8][tx] = in[(size_t)(r0 + ty + i * 8) * C + c0 + tx];
    __syncthreads();
#pragma unroll
    for (int i = 0; i < 4; i++)
        out[(size_t)(c0 + ty + i * 8) * R + r0 + tx] = (__bf16)tile[tx][ty + i * 8];
}

// ---------------------------------------------------------------------------
// Fill null-K row (kv==2048) with null_k, and zero Vt pad columns [2048,2056)
// ---------------------------------------------------------------------------
__global__ __launch_bounds__(256) void fill_null(
    const float* __restrict__ null_k, __bf16* __restrict__ Kb,
    __bf16* __restrict__ Vt)
{
    const int i = blockIdx.x * 256 + threadIdx.x;
    if (i < BATCH * DM) {
        const int b = i >> 10, d = i & (DM - 1);
        Kb[((size_t)b * NKV1 + NKVS) * DM + d] = (__bf16)null_k[d];
    }
    if (i < BATCH * NH * DHD * 8) {  // 16384
        const int bhd = i >> 3, kvp = i & 7;
        Vt[(size_t)bhd * 2056 + 2048 + kvp] = (__bf16)0.0f;
    }
}

// ---------------------------------------------------------------------------
// GEMM  C = A @ Bt^T + bias   (A: [M][K] bf16, Bt: [N][K] bf16)
// 128x128 tile, BK=32, 256 threads (4 waves, 64x64 each), mfma 16x16x32 bf16.
// Staging via global_load_lds width=16 (LDS layout = tid*16 bytes, unpadded).
// MODE 0: bf16 flat [M][N]
// MODE 3: f32 out with += resid
// MODE 4: split-K partials -- blockIdx.z = K-slice (K/4); raw f32 partial to
//         outp[(z*M + row)*N + col], no bias/act.  (occupancy fix: 1->4 bl/CU)
// ACT 1: exact GELU
// ---------------------------------------------------------------------------
template<int MODE, int ACT>
__global__ __launch_bounds__(256) void gemm_bt(
    const __bf16* __restrict__ A, const __bf16* __restrict__ Bt,
    const float* __restrict__ bias, void* __restrict__ outp,
    const float* __restrict__ resid, int M, int N, int K)
{
    __shared__ __bf16 As[128][32];
    __shared__ __bf16 Bs[128][32];
    const int tid  = threadIdx.x;
    const int lane = tid & 63, wave = tid >> 6;
    const int g = lane >> 4, c = lane & 15;
    const int m0 = blockIdx.y * 128, n0 = blockIdx.x * 128;
    const int wm = (wave >> 1) * 64, wn = (wave & 1) * 64;

    floatx4 acc[4][4] = {};

    const int srow = tid >> 2;
    const int schk = (tid & 3) * 8;
    const __bf16* Ag = A  + (size_t)(m0 + srow) * K + schk;
    const __bf16* Bg = Bt + (size_t)(n0 + srow) * K + schk;
    __bf16* lA0 = &As[srow][schk];
    __bf16* lA1 = &As[srow + 64][schk];
    __bf16* lB0 = &Bs[srow][schk];
    __bf16* lB1 = &Bs[srow + 64][schk];

    int kbeg = 0, kend = K;
    if (MODE == 4) { const int KS = K >> 2; kbeg = blockIdx.z * KS; kend = kbeg + KS; }

    for (int k0 = kbeg; k0 < kend; k0 += 32) {
        __syncthreads();
        gld_lds16(Ag + k0, lA0);
        gld_lds16(Ag + (size_t)64 * K + k0, lA1);
        gld_lds16(Bg + k0, lB0);
        gld_lds16(Bg + (size_t)64 * K + k0, lB1);
        __syncthreads();
        bf16x8 af[4], bfr[4];
#pragma unroll
        for (int i = 0; i < 4; i++) af[i]  = *(const bf16x8*)&As[wm + i * 16 + c][g * 8];
#pragma unroll
        for (int j = 0; j < 4; j++) bfr[j] = *(const bf16x8*)&Bs[wn + j * 16 + c][g * 8];
#pragma unroll
        for (int i = 0; i < 4; i++)
#pragma unroll
            for (int j = 0; j < 4; j++)
                acc[i][j] = __builtin_amdgcn_mfma_f32_16x16x32_bf16(af[i], bfr[j], acc[i][j], 0, 0, 0);
    }

    __bf16* obf = (__bf16*)outp;
    float*  of  = (float*)outp;
#pragma unroll
    for (int i = 0; i < 4; i++) {
#pragma unroll
        for (int j = 0; j < 4; j++) {
            const int row = m0 + wm + i * 16 + g * 4;
            const int col = n0 + wn + j * 16 + c;
            const float bb = (MODE == 4) ? 0.0f : bias[col];
            float xs[4];
#pragma unroll
            for (int r = 0; r < 4; r++) {
                float x = acc[i][j][r] + bb;
                if (ACT == 1) x = 0.5f * x * (1.0f + erff(x * 0.70710678118654752f));
                xs[r] = x;
            }
            if (MODE == 0) {
#pragma unroll
                for (int r = 0; r < 4; r++)
                    obf[(size_t)(row + r) * N + col] = (__bf16)xs[r];
            } else if (MODE == 3) {
#pragma unroll
                for (int r = 0; r < 4; r++) {
                    const size_t idx = (size_t)(row + r) * N + col;
                    of[idx] = xs[r] + resid[idx];
                }
            } else if (MODE == 4) {
#pragma unroll
                for (int r = 0; r < 4; r++)
                    of[((size_t)blockIdx.z * M + row + r) * N + col] = xs[r];
            }
        }
    }
}

// ---------------------------------------------------------------------------
// Fused Q/K/V projection GEMM.  Same 128x128 body; grid (8, 32, 3) = 768
// blocks = 3 blocks/CU (was 3 launches x 256 blocks = 1 block/CU each).
// z=0: Q -> Qbf flat; z=1: K -> Kbf row-padded; z=2: V -> Vt transposed.
// ---------------------------------------------------------------------------
__global__ __launch_bounds__(256) void qkv_gemm(
    const __bf16* __restrict__ Xn, const __bf16* __restrict__ Yn,
    const __bf16* __restrict__ WqT, const __bf16* __restrict__ WkT,
    const __bf16* __restrict__ WvT,
    const float* __restrict__ bq, const float* __restrict__ bk,
    const float* __restrict__ bv,
    __bf16* __restrict__ Qbf, __bf16* __restrict__ Kbf,
    __bf16* __restrict__ Vt)
{
    __shared__ __bf16 As[128][32];
    __shared__ __bf16 Bs[128][32];
    const int z = blockIdx.z;
    const __bf16* A    = (z == 0) ? Xn  : Yn;
    const __bf16* Bt   = (z == 0) ? WqT : (z == 1) ? WkT : WvT;
    const float*  bias = (z == 0) ? bq  : (z == 1) ? bk  : bv;

    const int tid  = threadIdx.x;
    const int lane = tid & 63, wave = tid >> 6;
    const int g = lane >> 4, c = lane & 15;
    const int m0 = blockIdx.y * 128, n0 = blockIdx.x * 128;
    const int wm = (wave >> 1) * 64, wn = (wave & 1) * 64;

    floatx4 acc[4][4] = {};

    const int srow = tid >> 2;
    const int schk = (tid & 3) * 8;
    const __bf16* Ag = A  + (size_t)(m0 + srow) * DM + schk;
    const __bf16* Bg = Bt + (size_t)(n0 + srow) * DM + schk;
    __bf16* lA0 = &As[srow][schk];
    __bf16* lA1 = &As[srow + 64][schk];
    __bf16* lB0 = &Bs[srow][schk];
    __bf16* lB1 = &Bs[srow + 64][schk];

    for (int k0 = 0; k0 < DM; k0 += 32) {
        __syncthreads();
        gld_lds16(Ag + k0, lA0);
        gld_lds16(Ag + (size_t)64 * DM + k0, lA1);
        gld_lds16(Bg + k0, lB0);
        gld_lds16(Bg + (size_t)64 * DM + k0, lB1);
        __syncthreads();
        bf16x8 af[4], bfr[4];
#pragma unroll
        for (int i = 0; i < 4; i++) af[i]  = *(const bf16x8*)&As[wm + i * 16 + c][g * 8];
#pragma unroll
        for (int j = 0; j < 4; j++) bfr[j] = *(const bf16x8*)&Bs[wn + j * 16 + c][g * 8];
#pragma unroll
        for (int i = 0; i < 4; i++)
#pragma unroll
            for (int j = 0; j < 4; j++)
                acc[i][j] = __builtin_amdgcn_mfma_f32_16x16x32_bf16(af[i], bfr[j], acc[i][j], 0, 0, 0);
    }

#pragma unroll
    for (int i = 0; i < 4; i++) {
#pragma unroll
        for (int j = 0; j < 4; j++) {
            const int row = m0 + wm + i * 16 + g * 4;
            const int col = n0 + wn + j * 16 + c;
            const float bb = bias[col];
            float xs[4];
#pragma unroll
            for (int r = 0; r < 4; r++) xs[r] = acc[i][j][r] + bb;
            if (z == 0) {
#pragma unroll
                for (int r = 0; r < 4; r++)
                    Qbf[(size_t)(row + r) * DM + col] = (__bf16)xs[r];
            } else if (z == 1) {
#pragma unroll
                for (int r = 0; r < 4; r++) {
                    const int rr = row + r;
                    Kbf[(size_t)(rr + (rr >> 11)) * DM + col] = (__bf16)xs[r];
                }
            } else {
                const int b  = row >> 11;
                const int kv = row & 2047;
                const size_t base =
                    ((size_t)((b * NH + (col >> 6)) * DHD + (col & 63))) * 2056 + kv;
                bf16x4 pk;
                pk[0] = (__bf16)xs[0]; pk[1] = (__bf16)xs[1];
                pk[2] = (__bf16)xs[2]; pk[3] = (__bf16)xs[3];
                *(bf16x4*)(Vt + base) = pk;
            }
        }
    }
}

// ---------------------------------------------------------------------------
// FF2 split-K reduction: out = sum_z partials[z] + bias + Hres.  float4/thread.
// ---------------------------------------------------------------------------
__global__ __launch_bounds__(256) void ff2_reduce(
    const float* __restrict__ part, const float* __restrict__ bias,
    const float* __restrict__ Hres, float* __restrict__ out)
{
    const size_t f4 = (size_t)blockIdx.x * 256 + threadIdx.x;  // float4 index
    const int c4 = (int)(f4 & (DM / 4 - 1));
    const size_t stride4 = (size_t)ROWS * DM / 4;
    float4 a = ((const float4*)part)[f4];
    const float4 p1 = ((const float4*)part)[f4 + stride4];
    const float4 p2 = ((const float4*)part)[f4 + 2 * stride4];
    const float4 p3 = ((const float4*)part)[f4 + 3 * stride4];
    const float4 b  = ((const float4*)bias)[c4];
    const float4 hr = ((const float4*)Hres)[f4];
    a.x += p1.x + p2.x + p3.x + b.x + hr.x;
    a.y += p1.y + p2.y + p3.y + b.y + hr.y;
    a.z += p1.z + p2.z + p3.z + b.z + hr.z;
    a.w += p1.w + p2.w + p3.w + b.w + hr.w;
    ((float4*)out)[f4] = a;
}

// ---------------------------------------------------------------------------
// Flash attention, S^T formulation.  grid (NQ/64, H, B), 256 threads (4 waves).
// ---------------------------------------------------------------------------
__global__ __launch_bounds__(256, 4) void attn_kernel(
    const __bf16* __restrict__ Q, const __bf16* __restrict__ Kb,
    const __bf16* __restrict__ Vt, __bf16* __restrict__ O)
{
    __shared__ __bf16 Ks[64][72];
    __shared__ __bf16 Vs[64][72];

    const int tid = threadIdx.x, lane = tid & 63, w = tid >> 6;
    const int g = lane >> 4, c = lane & 15;
    const int h = blockIdx.y, b = blockIdx.z;
    const int q0w = blockIdx.x * 64 + w * 16;

    bf16x8 qf[2];
    const __bf16* Qbase = Q + ((size_t)(b * NQS + q0w + c)) * DM + h * DHD;
    qf[0] = *(const bf16x8*)(Qbase + g * 8);
    qf[1] = *(const bf16x8*)(Qbase + 32 + g * 8);

    float m_i = -1e30f, l_i = 0.0f;
    floatx4 oacc[4] = {};

    const int kr = tid >> 3, kch = (tid & 7) * 8;
    const int vd = tid >> 2, vch = (tid & 3) * 8;
    const __bf16* Kb_base = Kb + (size_t)b * NKV1 * DM + h * DHD + kch;
    const __bf16* Vt_base = Vt + ((size_t)(b * NH + h) * DHD + vd) * 2056 + vch;
    const uint4 zero4 = make_uint4(0u, 0u, 0u, 0u);

    for (int it = 0; it < 33; it++) {
        const int kv0 = it * 64;
        __syncthreads();
        {
            const int kv1 = kv0 + kr, kv2 = kv1 + 32;
            uint4 ka  = (kv1 < NKV1) ? *(const uint4*)(Kb_base + (size_t)kv1 * DM) : zero4;
            uint4 kb2 = (kv2 < NKV1) ? *(const uint4*)(Kb_base + (size_t)kv2 * DM) : zero4;
            *(uint4*)&Ks[kr][kch]      = ka;
            *(uint4*)&Ks[kr + 32][kch] = kb2;
            uint4 vv0 = (kv0 + vch + 7  < 2056) ? *(const uint4*)(Vt_base + kv0)      : zero4;
            uint4 vv1 = (kv0 + vch + 39 < 2056) ? *(const uint4*)(Vt_base + kv0 + 32) : zero4;
            *(uint4*)&Vs[vd][vch]      = vv0;
            *(uint4*)&Vs[vd][vch + 32] = vv1;
        }
        __syncthreads();

        floatx4 s[4] = {};
        bf16x8 kf[4][2];
#pragma unroll
        for (int kvt = 0; kvt < 4; kvt++) {
            kf[kvt][0] = *(const bf16x8*)&Ks[kvt * 16 + c][g * 8];
            kf[kvt][1] = *(const bf16x8*)&Ks[kvt * 16 + c][32 + g * 8];
        }
#pragma unroll
        for (int kvt = 0; kvt < 4; kvt++) {
            s[kvt] = __builtin_amdgcn_mfma_f32_16x16x32_bf16(kf[kvt][0], qf[0], s[kvt], 0, 0, 0);
            s[kvt] = __builtin_amdgcn_mfma_f32_16x16x32_bf16(kf[kvt][1], qf[1], s[kvt], 0, 0, 0);
        }

#pragma unroll
        for (int kvt = 0; kvt < 4; kvt++)
#pragma unroll
            for (int r = 0; r < 4; r++)
                s[kvt][r] *= 0.03125f;
        if (kv0 + 64 > NKV1) {
#pragma unroll
            for (int kvt = 0; kvt < 4; kvt++)
#pragma unroll
                for (int r = 0; r < 4; r++)
                    if (kv0 + kvt * 16 + g * 4 + r >= NKV1) s[kvt][r] = -1e30f;
        }

        float t0 = fmaxf(fmaxf(s[0][0], s[0][1]), fmaxf(s[0][2], s[0][3]));
        float t1 = fmaxf(fmaxf(s[1][0], s[1][1]), fmaxf(s[1][2], s[1][3]));
        float t2 = fmaxf(fmaxf(s[2][0], s[2][1]), fmaxf(s[2][2], s[2][3]));
        float t3 = fmaxf(fmaxf(s[3][0], s[3][1]), fmaxf(s[3][2], s[3][3]));
        float tmax = fmaxf(fmaxf(t0, t1), fmaxf(t2, t3));
        tmax = fmaxf(tmax, __shfl_xor(tmax, 16));
        tmax = fmaxf(tmax, __shfl_xor(tmax, 32));

        const float mn = fmaxf(m_i, tmax);
        const float alpha = __expf(m_i - mn);
        m_i = mn;

        float rsum = 0.0f;
        shortx4 pf[4];
#pragma unroll
        for (int kvt = 0; kvt < 4; kvt++) {
            bf16x4 pb;
#pragma unroll
            for (int r = 0; r < 4; r++) {
                const float p = __expf(s[kvt][r] - mn);
                rsum += p;
                pb[r] = (__bf16)p;
            }
            pf[kvt] = __builtin_bit_cast(shortx4, pb);
        }
        rsum += __shfl_xor(rsum, 16);
        rsum += __shfl_xor(rsum, 32);
        l_i = l_i * alpha + rsum;

#pragma unroll
        for (int dt = 0; dt < 4; dt++)
#pragma unroll
            for (int r = 0; r < 4; r++)
                oacc[dt][r] *= alpha;

#pragma unroll
        for (int kvt = 0; kvt < 4; kvt++) {
            shortx4 vfr[4];
#pragma unroll
            for (int dt = 0; dt < 4; dt++)
                vfr[dt] = *(const shortx4*)&Vs[dt * 16 + c][kvt * 16 + g * 4];
#pragma unroll
            for (int dt = 0; dt < 4; dt++)
                oacc[dt] = __builtin_amdgcn_mfma_f32_16x16x16bf16_1k(
                    vfr[dt], pf[kvt], oacc[dt], 0, 0, 0);
        }
    }

    const float inv_l = 1.0f / l_i;
    __bf16* Ob = O + ((size_t)(b * NQS + q0w + c)) * DM + h * DHD;
#pragma unroll
    for (int dt = 0; dt < 4; dt++) {
        bf16x4 ob;
#pragma unroll
        for (int r = 0; r < 4; r++) ob[r] = (__bf16)(oacc[dt][r] * inv_l);
        *(bf16x4*)(Ob + dt * 16 + g * 4) = ob;
    }
}

// ---------------------------------------------------------------------------
extern "C" void kernel_launch(void* const* d_in, const int* in_sizes, int n_in,
                              void* d_out, int out_size, void* d_ws, size_t ws_size,
                              hipStream_t stream)
{
    const float* X      = (const float*)d_in[0];
    const float* Y      = (const float*)d_in[1];
    const float* Wq     = (const float*)d_in[2];
    const float* bq     = (const float*)d_in[3];
    const float* Wk     = (const float*)d_in[4];
    const float* bk     = (const float*)d_in[5];
    const float* Wv     = (const float*)d_in[6];
    const float* bv     = (const float*)d_in[7];
    const float* null_k = (const float*)d_in[8];
    const float* g0     = (const float*)d_in[9];
    const float* b0     = (const float*)d_in[10];
    const float* g0kv   = (const float*)d_in[11];
    const float* b0kv   = (const float*)d_in[12];
    const float* g1     = (const float*)d_in[13];
    const float* b1     = (const float*)d_in[14];
    const float* W1     = (const float*)d_in[15];
    const float* bf1    = (const float*)d_in[16];
    const float* W2     = (const float*)d_in[17];
    const float* bf2    = (const float*)d_in[18];
    float* out = (float*)d_out;

    // workspace carve (bytes).  Persistent-through-FF2 buffers FIRST so the
    // tail region (dead by FF2 time) can be reused for split-K partials.
    char* p = (char*)d_ws;
    __bf16* W2T  = (__bf16*)p; p += (size_t)4 * DM * DM * 2;          // [1024][4096]
    float*  Hres = (float*)p;  p += (size_t)ROWS * DM * 4;
    __bf16* Gbf  = (__bf16*)p; p += (size_t)ROWS * 4 * DM * 2;
    char* scratch = p;                                                // dead by FF2
    __bf16* Xn   = (__bf16*)p; p += (size_t)ROWS * DM * 2;
    __bf16* Yn   = (__bf16*)p; p += (size_t)ROWS * DM * 2;
    __bf16* WqT  = (__bf16*)p; p += (size_t)DM * DM * 2;
    __bf16* WkT  = (__bf16*)p; p += (size_t)DM * DM * 2;
    __bf16* WvT  = (__bf16*)p; p += (size_t)DM * DM * 2;
    __bf16* W1T  = (__bf16*)p; p += (size_t)4 * DM * DM * 2;          // [4096][1024]
    __bf16* Qbf  = (__bf16*)p; p += (size_t)ROWS * DM * 2;
    __bf16* Kbf  = (__bf16*)p; p += (size_t)BATCH * NKV1 * DM * 2;
    __bf16* Vt   = (__bf16*)p; p += (size_t)BATCH * NH * DHD * 2056 * 2;
    __bf16* Obf  = (__bf16*)p; p += (size_t)ROWS * DM * 2;
    __bf16* Hr   = (__bf16*)p; p += (size_t)ROWS * DM * 2;
    float* Part = (float*)scratch;   // 4 x ROWS x DM f32 = 67.1 MB <= scratch 73.4 MB

    // 1. LayerNorms
    ln_to_bf16<<<ROWS, 256, 0, stream>>>(X, g0, b0, Xn);
    ln_to_bf16<<<ROWS, 256, 0, stream>>>(Y, g0kv, b0kv, Yn);

    // 2. weight transposes (f32 -> bf16, W^T)
    transpose_f32_bf16<<<dim3(DM / 32, DM / 32), dim3(32, 8), 0, stream>>>(Wq, WqT, DM, DM);
    transpose_f32_bf16<<<dim3(DM / 32, DM / 32), dim3(32, 8), 0, stream>>>(Wk, WkT, DM, DM);
    transpose_f32_bf16<<<dim3(DM / 32, DM / 32), dim3(32, 8), 0, stream>>>(Wv, WvT, DM, DM);
    transpose_f32_bf16<<<dim3(4 * DM / 32, DM / 32), dim3(32, 8), 0, stream>>>(W1, W1T, DM, 4 * DM);
    transpose_f32_bf16<<<dim3(DM / 32, 4 * DM / 32), dim3(32, 8), 0, stream>>>(W2, W2T, 4 * DM, DM);

    // 3. fused Q/K/V projections (768 blocks = 3 blocks/CU)
    qkv_gemm<<<dim3(DM / 128, ROWS / 128, 3), 256, 0, stream>>>(
        Xn, Yn, WqT, WkT, WvT, bq, bk, bv, Qbf, Kbf, Vt);
    fill_null<<<64, 256, 0, stream>>>(null_k, Kbf, Vt);

    // 4. attention
    attn_kernel<<<dim3(NQS / 64, NH, BATCH), 256, 0, stream>>>(Qbf, Kbf, Vt, Obf);

    // 5. residual + LN
    resid_ln<<<ROWS, 256, 0, stream>>>(X, Obf, g1, b1, Hres, Hr);

    // 6. FFN
    gemm_bt<0, 1><<<dim3(4 * DM / 128, ROWS / 128), 256, 0, stream>>>(
        Hr, W1T, bf1, (void*)Gbf, nullptr, ROWS, 4 * DM, DM);
    // FF2 split-K=4 (1024 blocks = 4 blocks/CU), then reduce + bias + resid
    gemm_bt<4, 0><<<dim3(DM / 128, ROWS / 128, 4), 256, 0, stream>>>(
        Gbf, W2T, bf2, (void*)Part, nullptr, ROWS, DM, 4 * DM);
    ff2_reduce<<<ROWS * DM / 1024, 256, 0, stream>>>(Part, bf2, Hres, out);
}